// Round 5
// baseline (9028.727 us; speedup 1.0000x reference)
//
#include <hip/hip_runtime.h>
#include <hip/hip_fp16.h>
#include <math.h>

// Problem dims
#define B_  32
#define S_  256
#define I_  256
#define H_  512
#define N_  128
#define C_  64
#define O_  256
#define P_  268          // 4*C + 12
#define K_  832          // I + C + H
#define HB  (H_*B_)      // 16384
#define EPSX 1e-8f
#define NBLK 160         // 32 PB blocks + 128 gate blocks
#define NPB  32
#define NGATE 128
#define MST  68          // LDS M row stride (bank-spread padding)

// Workspace layout (float offsets) — unchanged from baseline.
#define OFF_XT   0
#define SZ_XT    (S_*I_*B_)
#define OFF_HA   (OFF_XT + SZ_XT)
#define SZ_HA    ((S_+1)*H_*B_)
#define OFF_RA   (OFF_HA + SZ_HA)
#define SZ_RA    ((S_+1)*C_*B_)
#define OFF_CT   (OFF_RA + SZ_RA)
#define SZ_CT    (H_*B_)
#define OFF_M    (OFF_CT + SZ_CT)
#define SZ_M     (B_*N_*C_)
#define OFF_WR   (OFF_M + SZ_M)
#define SZ_W     (B_*N_)
#define OFF_WW   (OFF_WR + SZ_W)
#define OFF_BAR  (OFF_WW + SZ_W)
#define SZ_BAR   8192                       // flag_h[128] @ +0, flag_r[32] @ +4096 (stride 16)
#define OFF_WOT  (OFF_BAR + SZ_BAR)
#define SZ_WOT   ((H_+C_)*O_)
#define OFF_WHH  (OFF_WOT + SZ_WOT)
#define SZ_WHH   ((P_*H_)/2)

__device__ __forceinline__ float sigm(float x) { return 1.f / (1.f + expf(-x)); }
__device__ __forceinline__ float splus(float x) {
    return fmaxf(x, 0.f) + log1pf(expf(-fabsf(x)));
}
__device__ __forceinline__ float wave_max(float v) {
    #pragma unroll
    for (int s = 1; s < 64; s <<= 1) v = fmaxf(v, __shfl_xor(v, s, 64));
    return v;
}
__device__ __forceinline__ float wave_sum(float v) {
    #pragma unroll
    for (int s = 1; s < 64; s <<= 1) v += __shfl_xor(v, s, 64);
    return v;
}

// FULL-ISSUE spin filler (round-5): 4 independent FMA chains -> ~100% VALU
// issue during waits (old dependent 16-chain issued only 25% of cycles,
// which may read as "idle" to DPM -> downclock). A/B on the clock theory.
__device__ __forceinline__ void junkf(float& s0, float& s1, float& s2, float& s3) {
    #pragma unroll
    for (int d = 0; d < 4; ++d) {
        s0 = fmaf(s0, 1.0000001f, 1e-9f);
        s1 = fmaf(s1, 1.0000002f, 2e-9f);
        s2 = fmaf(s2, 1.0000003f, 3e-9f);
        s3 = fmaf(s3, 1.0000004f, 4e-9f);
    }
    asm volatile("" : "+v"(s0), "+v"(s1), "+v"(s2), "+v"(s3));
}

// ---- point-to-point flag wait (R3 scheme — best measured) -----------------
// Waves 0,1 poll one flag per lane; wave-wide __all detects completion;
// lane 0 mirrors into LDS; waves 2..7 hot-spin on the mirror.
__device__ __forceinline__ void wait_flags(unsigned* flags, int nf, unsigned tgt,
                                           volatile unsigned* ldsp, int tid)
{
    const int wv = tid >> 6, ln = tid & 63;
    float s0 = 1.f, s1 = 2.f, s2 = 3.f, s3 = (float)(tid + 1);
    if (wv < 2) {
        int idx = wv * 64 + ln;
        if (idx >= nf) idx = nf - 1;
        unsigned* p = &flags[idx * 16];
        for (;;) {
            unsigned v = __hip_atomic_load(p, __ATOMIC_RELAXED,
                                           __HIP_MEMORY_SCOPE_AGENT);
            if (__all((int)(v >= tgt))) break;
            junkf(s0, s1, s2, s3);
        }
        if (ln == 0) ldsp[wv] = tgt;
    } else {
        while (ldsp[0] < tgt || ldsp[1] < tgt) junkf(s0, s1, s2, s3);
    }
    __syncthreads();
}

// ---------------- prep: transpose x & W_out, fp16 W_head, init state -------
__global__ __launch_bounds__(256)
void prep_kernel(const float* __restrict__ x, const float* __restrict__ Wout,
                 const float* __restrict__ Whead, float* __restrict__ ws)
{
    int g = blockIdx.x * 256 + threadIdx.x;
    if (g < SZ_XT) {
        int b = g & 31, k = (g >> 5) & 255, t = g >> 13;
        ws[OFF_XT + g] = x[b * (S_*I_) + t * I_ + k];
        return;
    }
    g -= SZ_XT;
    if (g < SZ_WOT) {
        int o = g & 255, k = g >> 8;
        ws[OFF_WOT + g] = Wout[o * (H_ + C_) + k];
        return;
    }
    g -= SZ_WOT;
    if (g < HB)      { ws[OFF_HA + g] = 0.f;   return; }
    g -= HB;
    if (g < C_*B_)   { ws[OFF_RA + g] = 0.f;   return; }
    g -= C_*B_;
    if (g < SZ_CT)   { ws[OFF_CT + g] = 0.f;   return; }
    g -= SZ_CT;
    if (g < SZ_M)    { ws[OFF_M  + g] = 0.01f; return; }   // (unused now)
    g -= SZ_M;
    if (g < 2*SZ_W)  { ws[OFF_WR + g] = 0.f;   return; }
    g -= 2*SZ_W;
    if (g < SZ_BAR)  { ws[OFF_BAR + g] = 0.f;  return; }
    g -= SZ_BAR;
    if (g < P_ * H_) {
        ((__half*)(ws + OFF_WHH))[g] = __float2half(Whead[g]);
        return;
    }
}

// GEMM inner step: one k-column, 4 gate rows x 8 batches into acc.
#define GEMM_STEP(khat, ap) {                                             \
    const float4 a0 = *(const float4*)(ap);                               \
    const float4 a1 = *(const float4*)((ap) + 4);                         \
    const float2 w01 = *(const float2*)&Wt[(khat) * 18 + (rg << 2)];      \
    const float2 w23 = *(const float2*)&Wt[(khat) * 18 + (rg << 2) + 2];  \
    const float wv[4] = {w01.x, w01.y, w23.x, w23.y};                     \
    const float av[8] = {a0.x, a0.y, a0.z, a0.w, a1.x, a1.y, a1.z, a1.w}; \
    _Pragma("unroll")                                                     \
    for (int j = 0; j < 4; ++j)                                           \
        _Pragma("unroll")                                                 \
        for (int bb = 0; bb < 8; ++bb)                                    \
            acc[j][bb] += wv[j] * av[bb]; }

// ---------------- persistent sequential loop -------------------------------
// 160 blocks x 512 threads, point-to-point flag sync (R3 scheme).
// PB blocks keep M entirely in LDS (aliased over the unused Wt array):
// removes all per-step M L2 round-trips from the phase-B critical path.
__global__ __launch_bounds__(512)
void ntm_loop(const float* __restrict__ Wih, const float* __restrict__ Whh,
              const float* __restrict__ bl,  const float* __restrict__ bhead,
              float* __restrict__ ws)
{
    float* xT  = ws + OFF_XT;
    float* hA  = ws + OFF_HA;
    float* rA  = ws + OFF_RA;
    unsigned* bar = (unsigned*)(ws + OFF_BAR);
    unsigned* flag_h = bar;            // [128] stride 16
    unsigned* flag_r = bar + 4096;     // [32]  stride 16
    const unsigned short* whH = (const unsigned short*)(ws + OFF_WHH);

    __shared__ float Wt[K_ * 18];     // gate blocks: weights; PB: M storage
    __shared__ float p_lds[P_];
    __shared__ float wldsR[128];
    __shared__ float wldsW[128];
    __shared__ float h_lds[H_];       // PB: h staging; aliased scratch later
    __shared__ float r_acc[C_];       // PB: fused r accumulation
    __shared__ unsigned syncf[4];     // LDS flag mirrors

    const int tid  = threadIdx.x;
    const int bi   = blockIdx.x;
    const bool isPB = (bi < NPB);
    const int gi   = bi - NPB;        // gate block index 0..127

    if (tid < 4) syncf[tid] = 0;

    float* Mlds = Wt;                 // PB alias: M[128][MST] = 34.8 KB < 59.9 KB

    if (!isPB) {
        for (int idx = tid; idx < K_ * 16; idx += 512) {
            int rl = idx & 15, k = idx >> 4;
            int row = (rl & 3) * H_ + gi * 4 + (rl >> 2);
            float v = (k < I_ + C_) ? Wih[row * (I_ + C_) + k]
                                    : Whh[row * H_ + (k - (I_ + C_))];
            Wt[k * 18 + rl] = v;
        }
    } else {
        if (tid < N_) {
            wldsR[tid] = (tid == 0) ? 1.f : 0.f;
            wldsW[tid] = (tid == 0) ? 1.f : 0.f;
        }
        for (int idx = tid; idx < (N_ * C_) / 4; idx += 512) {
            const int n = idx >> 4;
            const int c = (idx & 15) << 2;
            float4 m4 = {0.01f, 0.01f, 0.01f, 0.01f};
            *(float4*)&Mlds[n * MST + c] = m4;
        }
    }
    __syncthreads();   // staging + syncf visible

    const int pair = tid >> 5;        // 0..15
    const int ks   = tid & 31;        // split-K lane
    const int rg   = pair >> 2;       // unit_local 0..3
    const int bg   = pair & 3;        // batch octet 0..3
    const int b0   = bg * 8;          // 8 batches per pair

    float acc[4][8];
    float cr[8] = {0,0,0,0,0,0,0,0};  // LSTM c (ks==0 lanes)
    float bI = 0, bF = 0, bG = 0, bO = 0;
    if (!isPB && ks == 0) {
        const int unit = gi * 4 + rg;
        bI = bl[unit];        bF = bl[H_ + unit];
        bG = bl[2*H_ + unit]; bO = bl[3*H_ + unit];
    }

    if (!isPB) {
        // pre-loop partial(0): x[0] + h[0](=0)
        #pragma unroll
        for (int j = 0; j < 4; ++j)
            #pragma unroll
            for (int bb = 0; bb < 8; ++bb) acc[j][bb] = 0.f;
        const float* xs = xT;
        const float* hs = hA;
        #pragma unroll
        for (int i = 0; i < 8; ++i) {
            const int k = ks + (i << 5);
            GEMM_STEP(k, xs + k * B_ + b0);
        }
        #pragma unroll
        for (int i = 0; i < 16; ++i) {
            const int k = ks + (i << 5);
            GEMM_STEP(320 + k, hs + k * B_ + b0);
        }

        // ================= gate block main loop =================
        for (int t = 0; t < S_; ++t) {
            // wait r[t] (32 PB flags); t=0 trivially satisfied
            wait_flags(flag_r, NPB, (unsigned)t, &syncf[0], tid);

            const float* rs = rA + (size_t)t * C_ * B_;
            #pragma unroll
            for (int i = 0; i < 2; ++i) {
                const int k = ks + (i << 5);
                GEMM_STEP(256 + k, rs + k * B_ + b0);
            }
            #pragma unroll
            for (int j = 0; j < 4; ++j)
                #pragma unroll
                for (int bb = 0; bb < 8; ++bb) {
                    float v = acc[j][bb];
                    v += __shfl_xor(v, 16, 64);
                    v += __shfl_xor(v, 8, 64);
                    v += __shfl_xor(v, 4, 64);
                    v += __shfl_xor(v, 2, 64);
                    v += __shfl_xor(v, 1, 64);
                    acc[j][bb] = v;
                }
            if (ks == 0) {
                const int unit = gi * 4 + rg;
                float hv[8];
                #pragma unroll
                for (int bb = 0; bb < 8; ++bb) {
                    float gI = acc[0][bb] + bI;
                    float gF = acc[1][bb] + bF;
                    float gG = acc[2][bb] + bG;
                    float gO = acc[3][bb] + bO;
                    float cN = sigm(gF) * cr[bb] + sigm(gI) * tanhf(gG);
                    hv[bb] = sigm(gO) * tanhf(cN);
                    cr[bb] = cN;
                }
                // publish as 4x 64-bit agent stores (half the ack count)
                float* dst = &hA[(size_t)(t + 1) * HB + unit * B_ + b0];
                #pragma unroll
                for (int q = 0; q < 4; ++q) {
                    union { float f[2]; unsigned long long u; } pk;
                    pk.f[0] = hv[2 * q]; pk.f[1] = hv[2 * q + 1];
                    __hip_atomic_store((unsigned long long*)(dst + 2 * q), pk.u,
                                       __ATOMIC_RELAXED, __HIP_MEMORY_SCOPE_AGENT);
                }
            }
            __syncthreads();           // drains every lane's h stores (vmcnt 0)
            if (tid == 0) {
                asm volatile("s_waitcnt vmcnt(0) lgkmcnt(0)" ::: "memory");
                __hip_atomic_store(&flag_h[gi * 16], (unsigned)(t + 1),
                                   __ATOMIC_RELAXED, __HIP_MEMORY_SCOPE_AGENT);
            }
            // wait full h[t+1] (128 gate flags), then next partial
            wait_flags(flag_h, NGATE, (unsigned)(t + 1), &syncf[2], tid);

            #pragma unroll
            for (int j = 0; j < 4; ++j)
                #pragma unroll
                for (int bb = 0; bb < 8; ++bb) acc[j][bb] = 0.f;
            if (t + 1 < S_) {
                const float* xs2 = xT + (size_t)(t + 1) * I_ * B_;
                const float* hs2 = hA + (size_t)(t + 1) * HB;
                #pragma unroll
                for (int i = 0; i < 8; ++i) {
                    const int k = ks + (i << 5);
                    GEMM_STEP(k, xs2 + k * B_ + b0);
                }
                #pragma unroll
                for (int i = 0; i < 16; ++i) {
                    const int k = ks + (i << 5);
                    GEMM_STEP(320 + k, hs2 + k * B_ + b0);
                }
            }
        }
        return;
    }

    // ================= PB block main loop =================
    const int b = bi;
    for (int t = 0; t < S_; ++t) {
        wait_flags(flag_h, NGATE, (unsigned)(t + 1), &syncf[0], tid);

        const float* hs = hA + (size_t)(t + 1) * HB;
        h_lds[tid] = __hip_atomic_load(&hs[tid * B_ + b], __ATOMIC_RELAXED,
                                       __HIP_MEMORY_SCOPE_AGENT);
        if (tid < C_) r_acc[tid] = 0.f;
        __syncthreads();

        // head GEMM (fp16 weights): p = W_head @ h + b_head, 2 thr/row
        {
            const int sub  = tid & 1;
            const int row0 = tid >> 1;
            const float* hb = &h_lds[sub * 256];
            #pragma unroll
            for (int rep = 0; rep < 2; ++rep) {
                const int row = (rep == 0) ? row0
                              : ((row0 < P_ - 256) ? row0 + 256 : -1);
                if (row >= 0) {
                    const unsigned short* wrow = whH + row * H_ + sub * 256;
                    float acch = 0.f;
                    #pragma unroll 4
                    for (int k2 = 0; k2 < 256; k2 += 8) {
                        float4 raw = *(const float4*)&wrow[k2];
                        const __half2* hp = (const __half2*)&raw;
                        float2 f0 = __half22float2(hp[0]);
                        float2 f1 = __half22float2(hp[1]);
                        float2 f2 = __half22float2(hp[2]);
                        float2 f3 = __half22float2(hp[3]);
                        acch += f0.x * hb[k2]     + f0.y * hb[k2 + 1]
                              + f1.x * hb[k2 + 2] + f1.y * hb[k2 + 3]
                              + f2.x * hb[k2 + 4] + f2.y * hb[k2 + 5]
                              + f3.x * hb[k2 + 6] + f3.y * hb[k2 + 7];
                    }
                    acch += __shfl_xor(acch, 1, 64);
                    if (sub == 0) p_lds[row] = acch + bhead[row];
                }
            }
        }
        __syncthreads();

        // dual-pass addressing: grp0=read head, grp1=write head (concurrent)
        {
            float* wtmpA = h_lds;            // alias (h_lds dead)
            float* sbufA = h_lds + 256;
            const int grp = (tid >> 7) & 1;
            const int l   = tid & 127;
            const bool act256 = (tid < 256);
            const int o = grp ? 70 : 0;
            const int widx = (tid >> 6) & 1;

            float z = 0.f, gate = 0.f, s0 = 0.f, s1 = 0.f, s2 = 0.f,
                  gamma = 1.f;
            if (act256) {
                float beta = splus(p_lds[o + 64]);
                gate = sigm(p_lds[o + 65]);
                float sa = p_lds[o + 66], sbv = p_lds[o + 67],
                      sc = p_lds[o + 68];
                float sm3 = fmaxf(sa, fmaxf(sbv, sc));
                float ea = __expf(sa - sm3), eb = __expf(sbv - sm3),
                      ec = __expf(sc - sm3);
                float es3 = ea + eb + ec;
                s0 = ea / es3; s1 = eb / es3; s2 = ec / es3;
                gamma = 1.f + splus(p_lds[o + 69]);
                float kk = 0.f;
                #pragma unroll 8
                for (int c = 0; c < C_; ++c) {
                    float kv = p_lds[o + c]; kk += kv * kv;
                }
                const float knorm = sqrtf(kk) + EPSX;
                float dot = 0.f, mm = 0.f;
                #pragma unroll
                for (int c = 0; c < C_; c += 4) {
                    float4 m4 = *(const float4*)&Mlds[l * MST + c];
                    dot += m4.x * p_lds[o + c]     + m4.y * p_lds[o + c + 1]
                         + m4.z * p_lds[o + c + 2] + m4.w * p_lds[o + c + 3];
                    mm  += m4.x * m4.x + m4.y * m4.y + m4.z * m4.z
                         + m4.w * m4.w;
                }
                z = beta * (dot / ((sqrtf(mm) + EPSX) * knorm));
            }
            float zm = wave_max(z);
            if (act256 && (tid & 63) == 0) sbufA[grp * 8 + widx] = zm;
            __syncthreads();
            const float zmax = fmaxf(sbufA[grp * 8], sbufA[grp * 8 + 1]);
            float ev = act256 ? __expf(z - zmax) : 0.f;
            float es = wave_sum(ev);
            if (act256 && (tid & 63) == 0) sbufA[grp * 8 + 2 + widx] = es;
            __syncthreads();
            const float esum = sbufA[grp * 8 + 2] + sbufA[grp * 8 + 3];
            if (act256) {
                float wc = ev / esum;
                float wprev = grp ? wldsW[l] : wldsR[l];
                wtmpA[grp * 128 + l] = gate * wc + (1.f - gate) * wprev;
            }
            __syncthreads();
            float wp = 0.f;
            if (act256) {
                float wsft = s0 * wtmpA[grp * 128 + ((l + 1) & 127)]
                           + s1 * wtmpA[grp * 128 + l]
                           + s2 * wtmpA[grp * 128 + ((l - 1) & 127)];
                wp = __powf(wsft + EPSX, gamma);
            }
            float ps = wave_sum(wp);
            if (act256 && (tid & 63) == 0) sbufA[grp * 8 + 4 + widx] = ps;
            __syncthreads();
            const float psum = sbufA[grp * 8 + 4] + sbufA[grp * 8 + 5];
            if (act256) {
                float wn = wp / psum;
                if (grp) wldsW[l] = wn; else wldsR[l] = wn;
            }
            __syncthreads();
        }

        // M = M*(1 - w_w e) + w_w a  (in LDS) with fused r accumulation
        for (int idx = tid; idx < (N_ * C_) / 4; idx += 512) {
            const int n = idx >> 4;
            const int c = (idx & 15) << 2;
            const float wwn = wldsW[n];
            const float wrn = wldsR[n];
            float4 m4 = *(float4*)&Mlds[n * MST + c];
            m4.x = m4.x * (1.f - wwn * sigm(p_lds[140 + c]))     + wwn * p_lds[204 + c];
            m4.y = m4.y * (1.f - wwn * sigm(p_lds[140 + c + 1])) + wwn * p_lds[204 + c + 1];
            m4.z = m4.z * (1.f - wwn * sigm(p_lds[140 + c + 2])) + wwn * p_lds[204 + c + 2];
            m4.w = m4.w * (1.f - wwn * sigm(p_lds[140 + c + 3])) + wwn * p_lds[204 + c + 3];
            *(float4*)&Mlds[n * MST + c] = m4;
            atomicAdd(&r_acc[c],     wrn * m4.x);
            atomicAdd(&r_acc[c + 1], wrn * m4.y);
            atomicAdd(&r_acc[c + 2], wrn * m4.z);
            atomicAdd(&r_acc[c + 3], wrn * m4.w);
        }
        __syncthreads();

        // publish r
        if (tid < C_)
            __hip_atomic_store(&rA[(size_t)(t + 1) * C_ * B_ + tid * B_ + b],
                               r_acc[tid], __ATOMIC_RELAXED,
                               __HIP_MEMORY_SCOPE_AGENT);
        __syncthreads();               // drain r stores (per-lane vmcnt0)
        if (tid == 0) {
            asm volatile("s_waitcnt vmcnt(0) lgkmcnt(0)" ::: "memory");
            __hip_atomic_store(&flag_r[b * 16], (unsigned)(t + 1),
                               __ATOMIC_RELAXED, __HIP_MEMORY_SCOPE_AGENT);
        }
    }
}

// ---------------- final output GEMM ----------------
__global__ __launch_bounds__(256)
void out_kernel(const float* __restrict__ ws, const float* __restrict__ bout,
                float* __restrict__ out)
{
    __shared__ float actL[(H_ + C_) * 16];
    const float* hA  = ws + OFF_HA;
    const float* rA  = ws + OFF_RA;
    const float* WoT = ws + OFF_WOT;
    const int t   = blockIdx.x >> 1;
    const int bh  = blockIdx.x & 1;
    const int tid = threadIdx.x;

    for (int idx = tid; idx < (H_ + C_) * 16; idx += 256) {
        const int k = idx >> 4, bl2 = idx & 15, b = bh * 16 + bl2;
        float v = (k < H_) ? hA[(size_t)(t + 1) * HB + k * B_ + b]
                           : rA[(size_t)(t + 1) * C_ * B_ + (k - H_) * B_ + b];
        actL[k * 16 + bl2] = v;
    }
    __syncthreads();

    const int ot = tid & 63, bt = tid >> 6;
    const int o0 = ot * 4, bl0 = bt * 4;
    float acc[4][4] = {{0,0,0,0},{0,0,0,0},{0,0,0,0},{0,0,0,0}};
    for (int k = 0; k < H_ + C_; ++k) {
        const float4 w4 = *(const float4*)&WoT[k * O_ + o0];
        const float4 a4 = *(const float4*)&actL[k * 16 + bl0];
        const float wv[4] = {w4.x, w4.y, w4.z, w4.w};
        const float av[4] = {a4.x, a4.y, a4.z, a4.w};
        #pragma unroll
        for (int j = 0; j < 4; ++j)
            #pragma unroll
            for (int bb = 0; bb < 4; ++bb)
                acc[j][bb] += wv[j] * av[bb];
    }
    const float4 bo = *(const float4*)&bout[o0];
    #pragma unroll
    for (int bb = 0; bb < 4; ++bb) {
        const int b = bh * 16 + bl0 + bb;
        float4 res;
        res.x = acc[0][bb] + bo.x;
        res.y = acc[1][bb] + bo.y;
        res.z = acc[2][bb] + bo.z;
        res.w = acc[3][bb] + bo.w;
        *(float4*)&out[((size_t)b * S_ + t) * O_ + o0] = res;
    }
}

extern "C" void kernel_launch(void* const* d_in, const int* in_sizes, int n_in,
                              void* d_out, int out_size, void* d_ws, size_t ws_size,
                              hipStream_t stream)
{
    const float* x    = (const float*)d_in[0];
    const float* Wih  = (const float*)d_in[1];
    const float* Whh  = (const float*)d_in[2];
    const float* bl   = (const float*)d_in[3];
    const float* Whd  = (const float*)d_in[4];
    const float* bhd  = (const float*)d_in[5];
    const float* Wout = (const float*)d_in[6];
    const float* bout = (const float*)d_in[7];
    float* ws  = (float*)d_ws;
    float* out = (float*)d_out;

    prep_kernel<<<10529, 256, 0, stream>>>(x, Wout, Whd, ws);

    void* args[] = { (void*)&Wih, (void*)&Whh, (void*)&bl,
                     (void*)&bhd, (void*)&ws };
    (void)hipLaunchCooperativeKernel((void*)ntm_loop, dim3(NBLK), dim3(512), args, 0, stream);

    out_kernel<<<512, 256, 0, stream>>>(ws, bout, out);
}

// Round 6
// 6600.784 us; speedup vs baseline: 1.3678x; 1.3678x over previous
//
#include <hip/hip_runtime.h>
#include <hip/hip_fp16.h>
#include <math.h>

// Problem dims
#define B_  32
#define S_  256
#define I_  256
#define H_  512
#define N_  128
#define C_  64
#define O_  256
#define P_  268          // 4*C + 12
#define K_  832          // I + C + H
#define HB  (H_*B_)      // 16384
#define EPSX 1e-8f
#define NBLK 160         // 32 PB blocks + 128 gate blocks
#define NPB  32
#define NGATE 128
#define MST  68          // LDS M row stride

// Workspace layout (float offsets) — unchanged from baseline.
#define OFF_XT   0
#define SZ_XT    (S_*I_*B_)
#define OFF_HA   (OFF_XT + SZ_XT)
#define SZ_HA    ((S_+1)*H_*B_)
#define OFF_RA   (OFF_HA + SZ_HA)
#define SZ_RA    ((S_+1)*C_*B_)
#define OFF_CT   (OFF_RA + SZ_RA)
#define SZ_CT    (H_*B_)
#define OFF_M    (OFF_CT + SZ_CT)
#define SZ_M     (B_*N_*C_)
#define OFF_WR   (OFF_M + SZ_M)
#define SZ_W     (B_*N_)
#define OFF_WW   (OFF_WR + SZ_W)
#define OFF_BAR  (OFF_WW + SZ_W)
#define SZ_BAR   8192                       // flag_h[128] @ +0, flag_r[32] @ +4096 (stride 16)
#define OFF_WOT  (OFF_BAR + SZ_BAR)
#define SZ_WOT   ((H_+C_)*O_)
#define OFF_WHH  (OFF_WOT + SZ_WOT)
#define SZ_WHH   ((P_*H_)/2)

__device__ __forceinline__ float sigm(float x) { return 1.f / (1.f + expf(-x)); }
__device__ __forceinline__ float splus(float x) {
    return fmaxf(x, 0.f) + log1pf(expf(-fabsf(x)));
}
__device__ __forceinline__ float wave_max(float v) {
    #pragma unroll
    for (int s = 1; s < 64; s <<= 1) v = fmaxf(v, __shfl_xor(v, s, 64));
    return v;
}
__device__ __forceinline__ float wave_sum(float v) {
    #pragma unroll
    for (int s = 1; s < 64; s <<= 1) v += __shfl_xor(v, s, 64);
    return v;
}

// R3's dependent-FMA poll filler (best measured spin style for pollers).
__device__ __forceinline__ void junk16(float& s) {
    #pragma unroll
    for (int d = 0; d < 16; ++d) s = fmaf(s, 1.0000001f, 1e-9f);
    asm volatile("" : "+v"(s));
}

// ---- point-to-point flag wait: poll waves + SLEEPING bystanders -----------
// R6 A/B on the power-throttle theory: waves 0,1 poll global flags with the
// R3 dependent-FMA filler; waves 2..7 (75% of spin population) s_sleep
// between LDS-mirror checks instead of burning FMA power. If R5's regression
// was power-side throttle, cutting spin power raises clocks -> faster.
__device__ __forceinline__ void wait_flags(unsigned* flags, int nf, unsigned tgt,
                                           volatile unsigned* ldsp, int tid)
{
    const int wv = tid >> 6, ln = tid & 63;
    if (wv < 2) {
        int idx = wv * 64 + ln;
        if (idx >= nf) idx = nf - 1;
        unsigned* p = &flags[idx * 16];
        float s = 1.f;
        for (;;) {
            unsigned v = __hip_atomic_load(p, __ATOMIC_RELAXED,
                                           __HIP_MEMORY_SCOPE_AGENT);
            if (__all((int)(v >= tgt))) break;
            junk16(s);
        }
        if (ln == 0) ldsp[wv] = tgt;
    } else {
        while (ldsp[0] < tgt || ldsp[1] < tgt)
            __builtin_amdgcn_s_sleep(2);    // ~128 cy low-power nap
    }
    __syncthreads();
}

// ---------------- prep: transpose x & W_out, fp16 W_head, init state -------
__global__ __launch_bounds__(256)
void prep_kernel(const float* __restrict__ x, const float* __restrict__ Wout,
                 const float* __restrict__ Whead, float* __restrict__ ws)
{
    int g = blockIdx.x * 256 + threadIdx.x;
    if (g < SZ_XT) {
        int b = g & 31, k = (g >> 5) & 255, t = g >> 13;
        ws[OFF_XT + g] = x[b * (S_*I_) + t * I_ + k];
        return;
    }
    g -= SZ_XT;
    if (g < SZ_WOT) {
        int o = g & 255, k = g >> 8;
        ws[OFF_WOT + g] = Wout[o * (H_ + C_) + k];
        return;
    }
    g -= SZ_WOT;
    if (g < HB)      { ws[OFF_HA + g] = 0.f;   return; }
    g -= HB;
    if (g < C_*B_)   { ws[OFF_RA + g] = 0.f;   return; }
    g -= C_*B_;
    if (g < SZ_CT)   { ws[OFF_CT + g] = 0.f;   return; }
    g -= SZ_CT;
    if (g < SZ_M)    { ws[OFF_M  + g] = 0.01f; return; }   // (unused: M in LDS)
    g -= SZ_M;
    if (g < 2*SZ_W)  { ws[OFF_WR + g] = 0.f;   return; }
    g -= 2*SZ_W;
    if (g < SZ_BAR)  { ws[OFF_BAR + g] = 0.f;  return; }
    g -= SZ_BAR;
    if (g < P_ * H_) {
        ((__half*)(ws + OFF_WHH))[g] = __float2half(Whead[g]);
        return;
    }
}

// GEMM inner step: one k-column, 4 gate rows x 8 batches into acc.
#define GEMM_STEP(khat, ap) {                                             \
    const float4 a0 = *(const float4*)(ap);                               \
    const float4 a1 = *(const float4*)((ap) + 4);                         \
    const float2 w01 = *(const float2*)&Wt[(khat) * 18 + (rg << 2)];      \
    const float2 w23 = *(const float2*)&Wt[(khat) * 18 + (rg << 2) + 2];  \
    const float wv[4] = {w01.x, w01.y, w23.x, w23.y};                     \
    const float av[8] = {a0.x, a0.y, a0.z, a0.w, a1.x, a1.y, a1.z, a1.w}; \
    _Pragma("unroll")                                                     \
    for (int j = 0; j < 4; ++j)                                           \
        _Pragma("unroll")                                                 \
        for (int bb = 0; bb < 8; ++bb)                                    \
            acc[j][bb] += wv[j] * av[bb]; }

// ---------------- persistent sequential loop -------------------------------
// 160 blocks x 512 threads, point-to-point flag sync (R3 scheme).
// PB blocks keep M in LDS (aliased over unused Wt); r via shuffle-reduce
// (NO LDS atomics — R5's 32-way same-address atomicAdd was a regression).
__global__ __launch_bounds__(512)
void ntm_loop(const float* __restrict__ Wih, const float* __restrict__ Whh,
              const float* __restrict__ bl,  const float* __restrict__ bhead,
              float* __restrict__ ws)
{
    float* xT  = ws + OFF_XT;
    float* hA  = ws + OFF_HA;
    float* rA  = ws + OFF_RA;
    unsigned* bar = (unsigned*)(ws + OFF_BAR);
    unsigned* flag_h = bar;            // [128] stride 16
    unsigned* flag_r = bar + 4096;     // [32]  stride 16
    const unsigned short* whH = (const unsigned short*)(ws + OFF_WHH);

    __shared__ float Wt[K_ * 18];     // gate blocks: weights; PB: M storage
    __shared__ float p_lds[P_];
    __shared__ float wldsR[128];
    __shared__ float wldsW[128];
    __shared__ float h_lds[H_];       // PB: h staging; aliased scratch later
    __shared__ unsigned syncf[4];     // LDS flag mirrors

    const int tid  = threadIdx.x;
    const int bi   = blockIdx.x;
    const bool isPB = (bi < NPB);
    const int gi   = bi - NPB;        // gate block index 0..127

    if (tid < 4) syncf[tid] = 0;

    float* Mlds = Wt;                 // PB alias: M[128][MST] = 34.8 KB

    if (!isPB) {
        for (int idx = tid; idx < K_ * 16; idx += 512) {
            int rl = idx & 15, k = idx >> 4;
            int row = (rl & 3) * H_ + gi * 4 + (rl >> 2);
            float v = (k < I_ + C_) ? Wih[row * (I_ + C_) + k]
                                    : Whh[row * H_ + (k - (I_ + C_))];
            Wt[k * 18 + rl] = v;
        }
    } else {
        if (tid < N_) {
            wldsR[tid] = (tid == 0) ? 1.f : 0.f;
            wldsW[tid] = (tid == 0) ? 1.f : 0.f;
        }
        for (int idx = tid; idx < (N_ * C_) / 4; idx += 512) {
            const int n = idx >> 4;
            const int c = (idx & 15) << 2;
            float4 m4 = {0.01f, 0.01f, 0.01f, 0.01f};
            *(float4*)&Mlds[n * MST + c] = m4;
        }
    }
    __syncthreads();   // staging + syncf visible

    const int pair = tid >> 5;        // 0..15
    const int ks   = tid & 31;        // split-K lane
    const int rg   = pair >> 2;       // unit_local 0..3
    const int bg   = pair & 3;        // batch octet 0..3
    const int b0   = bg * 8;          // 8 batches per pair

    float acc[4][8];
    float cr[8] = {0,0,0,0,0,0,0,0};  // LSTM c (ks==0 lanes)
    float bI = 0, bF = 0, bG = 0, bO = 0;
    if (!isPB && ks == 0) {
        const int unit = gi * 4 + rg;
        bI = bl[unit];        bF = bl[H_ + unit];
        bG = bl[2*H_ + unit]; bO = bl[3*H_ + unit];
    }

    if (!isPB) {
        // pre-loop partial(0): x[0] + h[0](=0)
        #pragma unroll
        for (int j = 0; j < 4; ++j)
            #pragma unroll
            for (int bb = 0; bb < 8; ++bb) acc[j][bb] = 0.f;
        const float* xs = xT;
        const float* hs = hA;
        #pragma unroll
        for (int i = 0; i < 8; ++i) {
            const int k = ks + (i << 5);
            GEMM_STEP(k, xs + k * B_ + b0);
        }
        #pragma unroll
        for (int i = 0; i < 16; ++i) {
            const int k = ks + (i << 5);
            GEMM_STEP(320 + k, hs + k * B_ + b0);
        }

        // ================= gate block main loop =================
        for (int t = 0; t < S_; ++t) {
            // wait r[t] (32 PB flags); t=0 trivially satisfied
            wait_flags(flag_r, NPB, (unsigned)t, &syncf[0], tid);

            const float* rs = rA + (size_t)t * C_ * B_;
            #pragma unroll
            for (int i = 0; i < 2; ++i) {
                const int k = ks + (i << 5);
                GEMM_STEP(256 + k, rs + k * B_ + b0);
            }
            #pragma unroll
            for (int j = 0; j < 4; ++j)
                #pragma unroll
                for (int bb = 0; bb < 8; ++bb) {
                    float v = acc[j][bb];
                    v += __shfl_xor(v, 16, 64);
                    v += __shfl_xor(v, 8, 64);
                    v += __shfl_xor(v, 4, 64);
                    v += __shfl_xor(v, 2, 64);
                    v += __shfl_xor(v, 1, 64);
                    acc[j][bb] = v;
                }
            if (ks == 0) {
                const int unit = gi * 4 + rg;
                float hv[8];
                #pragma unroll
                for (int bb = 0; bb < 8; ++bb) {
                    float gI = acc[0][bb] + bI;
                    float gF = acc[1][bb] + bF;
                    float gG = acc[2][bb] + bG;
                    float gO = acc[3][bb] + bO;
                    float cN = sigm(gF) * cr[bb] + sigm(gI) * tanhf(gG);
                    hv[bb] = sigm(gO) * tanhf(cN);
                    cr[bb] = cN;
                }
                // publish as 4x 64-bit agent stores (half the ack count)
                float* dst = &hA[(size_t)(t + 1) * HB + unit * B_ + b0];
                #pragma unroll
                for (int q = 0; q < 4; ++q) {
                    union { float f[2]; unsigned long long u; } pk;
                    pk.f[0] = hv[2 * q]; pk.f[1] = hv[2 * q + 1];
                    __hip_atomic_store((unsigned long long*)(dst + 2 * q), pk.u,
                                       __ATOMIC_RELAXED, __HIP_MEMORY_SCOPE_AGENT);
                }
            }
            __syncthreads();           // drains every lane's h stores (vmcnt 0)
            if (tid == 0) {
                asm volatile("s_waitcnt vmcnt(0) lgkmcnt(0)" ::: "memory");
                __hip_atomic_store(&flag_h[gi * 16], (unsigned)(t + 1),
                                   __ATOMIC_RELAXED, __HIP_MEMORY_SCOPE_AGENT);
            }
            // wait full h[t+1] (128 gate flags), then next partial
            wait_flags(flag_h, NGATE, (unsigned)(t + 1), &syncf[2], tid);

            #pragma unroll
            for (int j = 0; j < 4; ++j)
                #pragma unroll
                for (int bb = 0; bb < 8; ++bb) acc[j][bb] = 0.f;
            if (t + 1 < S_) {
                const float* xs2 = xT + (size_t)(t + 1) * I_ * B_;
                const float* hs2 = hA + (size_t)(t + 1) * HB;
                #pragma unroll
                for (int i = 0; i < 8; ++i) {
                    const int k = ks + (i << 5);
                    GEMM_STEP(k, xs2 + k * B_ + b0);
                }
                #pragma unroll
                for (int i = 0; i < 16; ++i) {
                    const int k = ks + (i << 5);
                    GEMM_STEP(320 + k, hs2 + k * B_ + b0);
                }
            }
        }
        return;
    }

    // ================= PB block main loop =================
    const int b = bi;
    for (int t = 0; t < S_; ++t) {
        wait_flags(flag_h, NGATE, (unsigned)(t + 1), &syncf[0], tid);

        const float* hs = hA + (size_t)(t + 1) * HB;
        h_lds[tid] = __hip_atomic_load(&hs[tid * B_ + b], __ATOMIC_RELAXED,
                                       __HIP_MEMORY_SCOPE_AGENT);
        __syncthreads();

        // head GEMM (fp16 weights): p = W_head @ h + b_head, 2 thr/row
        {
            const int sub  = tid & 1;
            const int row0 = tid >> 1;
            const float* hb = &h_lds[sub * 256];
            #pragma unroll
            for (int rep = 0; rep < 2; ++rep) {
                const int row = (rep == 0) ? row0
                              : ((row0 < P_ - 256) ? row0 + 256 : -1);
                if (row >= 0) {
                    const unsigned short* wrow = whH + row * H_ + sub * 256;
                    float acch = 0.f;
                    #pragma unroll 4
                    for (int k2 = 0; k2 < 256; k2 += 8) {
                        float4 raw = *(const float4*)&wrow[k2];
                        const __half2* hp = (const __half2*)&raw;
                        float2 f0 = __half22float2(hp[0]);
                        float2 f1 = __half22float2(hp[1]);
                        float2 f2 = __half22float2(hp[2]);
                        float2 f3 = __half22float2(hp[3]);
                        acch += f0.x * hb[k2]     + f0.y * hb[k2 + 1]
                              + f1.x * hb[k2 + 2] + f1.y * hb[k2 + 3]
                              + f2.x * hb[k2 + 4] + f2.y * hb[k2 + 5]
                              + f3.x * hb[k2 + 6] + f3.y * hb[k2 + 7];
                    }
                    acch += __shfl_xor(acch, 1, 64);
                    if (sub == 0) p_lds[row] = acch + bhead[row];
                }
            }
        }
        __syncthreads();

        // dual-pass addressing: grp0=read head, grp1=write head (concurrent)
        {
            float* wtmpA = h_lds;            // alias (h_lds dead)
            float* sbufA = h_lds + 256;
            const int grp = (tid >> 7) & 1;
            const int l   = tid & 127;
            const bool act256 = (tid < 256);
            const int o = grp ? 70 : 0;
            const int widx = (tid >> 6) & 1;

            float z = 0.f, gate = 0.f, s0 = 0.f, s1 = 0.f, s2 = 0.f,
                  gamma = 1.f;
            if (act256) {
                float beta = splus(p_lds[o + 64]);
                gate = sigm(p_lds[o + 65]);
                float sa = p_lds[o + 66], sbv = p_lds[o + 67],
                      sc = p_lds[o + 68];
                float sm3 = fmaxf(sa, fmaxf(sbv, sc));
                float ea = __expf(sa - sm3), eb = __expf(sbv - sm3),
                      ec = __expf(sc - sm3);
                float es3 = ea + eb + ec;
                s0 = ea / es3; s1 = eb / es3; s2 = ec / es3;
                gamma = 1.f + splus(p_lds[o + 69]);
                float kk = 0.f;
                #pragma unroll 8
                for (int c = 0; c < C_; ++c) {
                    float kv = p_lds[o + c]; kk += kv * kv;
                }
                const float knorm = sqrtf(kk) + EPSX;
                float dot = 0.f, mm = 0.f;
                #pragma unroll
                for (int c = 0; c < C_; c += 4) {
                    float4 m4 = *(const float4*)&Mlds[l * MST + c];
                    dot += m4.x * p_lds[o + c]     + m4.y * p_lds[o + c + 1]
                         + m4.z * p_lds[o + c + 2] + m4.w * p_lds[o + c + 3];
                    mm  += m4.x * m4.x + m4.y * m4.y + m4.z * m4.z
                         + m4.w * m4.w;
                }
                z = beta * (dot / ((sqrtf(mm) + EPSX) * knorm));
            }
            float zm = wave_max(z);
            if (act256 && (tid & 63) == 0) sbufA[grp * 8 + widx] = zm;
            __syncthreads();
            const float zmax = fmaxf(sbufA[grp * 8], sbufA[grp * 8 + 1]);
            float ev = act256 ? __expf(z - zmax) : 0.f;
            float es = wave_sum(ev);
            if (act256 && (tid & 63) == 0) sbufA[grp * 8 + 2 + widx] = es;
            __syncthreads();
            const float esum = sbufA[grp * 8 + 2] + sbufA[grp * 8 + 3];
            if (act256) {
                float wc = ev / esum;
                float wprev = grp ? wldsW[l] : wldsR[l];
                wtmpA[grp * 128 + l] = gate * wc + (1.f - gate) * wprev;
            }
            __syncthreads();
            float wp = 0.f;
            if (act256) {
                float wsft = s0 * wtmpA[grp * 128 + ((l + 1) & 127)]
                           + s1 * wtmpA[grp * 128 + l]
                           + s2 * wtmpA[grp * 128 + ((l - 1) & 127)];
                wp = __powf(wsft + EPSX, gamma);
            }
            float ps = wave_sum(wp);
            if (act256 && (tid & 63) == 0) sbufA[grp * 8 + 4 + widx] = ps;
            __syncthreads();
            const float psum = sbufA[grp * 8 + 4] + sbufA[grp * 8 + 5];
            if (act256) {
                float wn = wp / psum;
                if (grp) wldsW[l] = wn; else wldsR[l] = wn;
            }
            __syncthreads();
        }

        // M = M*(1 - w_w e) + w_w a   (in LDS, no atomics)
        for (int idx = tid; idx < (N_ * C_) / 4; idx += 512) {
            const int n = idx >> 4;
            const int c = (idx & 15) << 2;
            const float wwn = wldsW[n];
            float4 m4 = *(float4*)&Mlds[n * MST + c];
            m4.x = m4.x * (1.f - wwn * sigm(p_lds[140 + c]))     + wwn * p_lds[204 + c];
            m4.y = m4.y * (1.f - wwn * sigm(p_lds[140 + c + 1])) + wwn * p_lds[204 + c + 1];
            m4.z = m4.z * (1.f - wwn * sigm(p_lds[140 + c + 2])) + wwn * p_lds[204 + c + 2];
            m4.w = m4.w * (1.f - wwn * sigm(p_lds[140 + c + 3])) + wwn * p_lds[204 + c + 3];
            *(float4*)&Mlds[n * MST + c] = m4;
        }
        __syncthreads();

        // r = w_r @ M_new (LDS reads, shuffle reduce) -> publish
        {
            const int c = tid >> 3, ns = tid & 7;
            float accr = 0.f;
            #pragma unroll
            for (int i = 0; i < 16; ++i) {
                const int n = ns + 8 * i;
                accr += wldsR[n] * Mlds[n * MST + c];
            }
            accr += __shfl_xor(accr, 4, 64);
            accr += __shfl_xor(accr, 2, 64);
            accr += __shfl_xor(accr, 1, 64);
            if (ns == 0)
                __hip_atomic_store(&rA[(size_t)(t + 1) * C_ * B_ + c * B_ + b],
                                   accr, __ATOMIC_RELAXED,
                                   __HIP_MEMORY_SCOPE_AGENT);
        }
        __syncthreads();               // drain r stores
        if (tid == 0) {
            asm volatile("s_waitcnt vmcnt(0) lgkmcnt(0)" ::: "memory");
            __hip_atomic_store(&flag_r[b * 16], (unsigned)(t + 1),
                               __ATOMIC_RELAXED, __HIP_MEMORY_SCOPE_AGENT);
        }
    }
}

// ---------------- final output GEMM ----------------
__global__ __launch_bounds__(256)
void out_kernel(const float* __restrict__ ws, const float* __restrict__ bout,
                float* __restrict__ out)
{
    __shared__ float actL[(H_ + C_) * 16];
    const float* hA  = ws + OFF_HA;
    const float* rA  = ws + OFF_RA;
    const float* WoT = ws + OFF_WOT;
    const int t   = blockIdx.x >> 1;
    const int bh  = blockIdx.x & 1;
    const int tid = threadIdx.x;

    for (int idx = tid; idx < (H_ + C_) * 16; idx += 256) {
        const int k = idx >> 4, bl2 = idx & 15, b = bh * 16 + bl2;
        float v = (k < H_) ? hA[(size_t)(t + 1) * HB + k * B_ + b]
                           : rA[(size_t)(t + 1) * C_ * B_ + (k - H_) * B_ + b];
        actL[k * 16 + bl2] = v;
    }
    __syncthreads();

    const int ot = tid & 63, bt = tid >> 6;
    const int o0 = ot * 4, bl0 = bt * 4;
    float acc[4][4] = {{0,0,0,0},{0,0,0,0},{0,0,0,0},{0,0,0,0}};
    for (int k = 0; k < H_ + C_; ++k) {
        const float4 w4 = *(const float4*)&WoT[k * O_ + o0];
        const float4 a4 = *(const float4*)&actL[k * 16 + bl0];
        const float wv[4] = {w4.x, w4.y, w4.z, w4.w};
        const float av[4] = {a4.x, a4.y, a4.z, a4.w};
        #pragma unroll
        for (int j = 0; j < 4; ++j)
            #pragma unroll
            for (int bb = 0; bb < 4; ++bb)
                acc[j][bb] += wv[j] * av[bb];
    }
    const float4 bo = *(const float4*)&bout[o0];
    #pragma unroll
    for (int bb = 0; bb < 4; ++bb) {
        const int b = bh * 16 + bl0 + bb;
        float4 res;
        res.x = acc[0][bb] + bo.x;
        res.y = acc[1][bb] + bo.y;
        res.z = acc[2][bb] + bo.z;
        res.w = acc[3][bb] + bo.w;
        *(float4*)&out[((size_t)b * S_ + t) * O_ + o0] = res;
    }
}

extern "C" void kernel_launch(void* const* d_in, const int* in_sizes, int n_in,
                              void* d_out, int out_size, void* d_ws, size_t ws_size,
                              hipStream_t stream)
{
    const float* x    = (const float*)d_in[0];
    const float* Wih  = (const float*)d_in[1];
    const float* Whh  = (const float*)d_in[2];
    const float* bl   = (const float*)d_in[3];
    const float* Whd  = (const float*)d_in[4];
    const float* bhd  = (const float*)d_in[5];
    const float* Wout = (const float*)d_in[6];
    const float* bout = (const float*)d_in[7];
    float* ws  = (float*)d_ws;
    float* out = (float*)d_out;

    prep_kernel<<<10529, 256, 0, stream>>>(x, Wout, Whd, ws);

    void* args[] = { (void*)&Wih, (void*)&Whh, (void*)&bl,
                     (void*)&bhd, (void*)&ws };
    (void)hipLaunchCooperativeKernel((void*)ntm_loop, dim3(NBLK), dim3(512), args, 0, stream);

    out_kernel<<<512, 256, 0, stream>>>(ws, bout, out);
}

// Round 7
// 6599.013 us; speedup vs baseline: 1.3682x; 1.0003x over previous
//
#include <hip/hip_runtime.h>
#include <hip/hip_fp16.h>
#include <math.h>

// Problem dims
#define B_  32
#define S_  256
#define I_  256
#define H_  512
#define N_  128
#define C_  64
#define O_  256
#define P_  268          // 4*C + 12
#define K_  832          // I + C + H
#define HB  (H_*B_)      // 16384
#define EPSX 1e-8f
#define NBLK 160         // 32 PB blocks + 128 gate blocks
#define NPB  32
#define NGATE 128
#define MST  68          // LDS M row stride

// Workspace layout (float offsets) — unchanged from baseline.
#define OFF_XT   0
#define SZ_XT    (S_*I_*B_)
#define OFF_HA   (OFF_XT + SZ_XT)
#define SZ_HA    ((S_+1)*H_*B_)
#define OFF_RA   (OFF_HA + SZ_HA)
#define SZ_RA    ((S_+1)*C_*B_)
#define OFF_CT   (OFF_RA + SZ_RA)
#define SZ_CT    (H_*B_)                    // hT[b][unit] transposed h (per step)
#define OFF_M    (OFF_CT + SZ_CT)
#define SZ_M     (B_*N_*C_)
#define OFF_WR   (OFF_M + SZ_M)
#define SZ_W     (B_*N_)
#define OFF_WW   (OFF_WR + SZ_W)
#define OFF_BAR  (OFF_WW + SZ_W)
#define SZ_BAR   8192                       // flag_h[128] @ +0, flag_r[32] @ +4096 (stride 16)
#define OFF_WOT  (OFF_BAR + SZ_BAR)
#define SZ_WOT   ((H_+C_)*O_)
#define OFF_WHH  (OFF_WOT + SZ_WOT)
#define SZ_WHH   ((P_*H_)/2)

__device__ __forceinline__ float sigm(float x) { return 1.f / (1.f + expf(-x)); }
__device__ __forceinline__ float splus(float x) {
    return fmaxf(x, 0.f) + log1pf(expf(-fabsf(x)));
}
__device__ __forceinline__ float wave_max(float v) {
    #pragma unroll
    for (int s = 1; s < 64; s <<= 1) v = fmaxf(v, __shfl_xor(v, s, 64));
    return v;
}
__device__ __forceinline__ float wave_sum(float v) {
    #pragma unroll
    for (int s = 1; s < 64; s <<= 1) v += __shfl_xor(v, s, 64);
    return v;
}

// Dependent-FMA filler: low-power VALU activity (holds DPM boost).
__device__ __forceinline__ void junk16(float& s) {
    #pragma unroll
    for (int d = 0; d < 16; ++d) s = fmaf(s, 1.0000001f, 1e-9f);
    asm volatile("" : "+v"(s));
}

// ---- point-to-point flag wait, THROTTLED pollers + sleeping bystanders ----
// R7 theory: each poll wave's 64 lanes hit 64 DIFFERENT flag lines -> one
// wave-poll = 64 L3 transactions; ~320 polling waves = continuous fabric
// storm that queues ahead of producers' data/flag stores (inflates every
// hop). Fix: ~380cy of dependent FMA between polls (traffic /6, activity
// kept, +80ns detection latency). Waves 2..7 still s_sleep on LDS mirror.
__device__ __forceinline__ void wait_flags(unsigned* flags, int nf, unsigned tgt,
                                           volatile unsigned* ldsp, int tid)
{
    const int wv = tid >> 6, ln = tid & 63;
    if (wv < 2) {
        int idx = wv * 64 + ln;
        if (idx >= nf) idx = nf - 1;
        unsigned* p = &flags[idx * 16];
        float s = 1.f;
        for (;;) {
            unsigned v = __hip_atomic_load(p, __ATOMIC_RELAXED,
                                           __HIP_MEMORY_SCOPE_AGENT);
            if (__all((int)(v >= tgt))) break;
            junk16(s); junk16(s); junk16(s);
            junk16(s); junk16(s); junk16(s);
        }
        if (ln == 0) ldsp[wv] = tgt;
    } else {
        while (ldsp[0] < tgt || ldsp[1] < tgt)
            __builtin_amdgcn_s_sleep(2);    // ~128 cy low-power nap
    }
    __syncthreads();
}

// ---------------- prep: transpose x & W_out, fp16 W_head, init state -------
__global__ __launch_bounds__(256)
void prep_kernel(const float* __restrict__ x, const float* __restrict__ Wout,
                 const float* __restrict__ Whead, float* __restrict__ ws)
{
    int g = blockIdx.x * 256 + threadIdx.x;
    if (g < SZ_XT) {
        int b = g & 31, k = (g >> 5) & 255, t = g >> 13;
        ws[OFF_XT + g] = x[b * (S_*I_) + t * I_ + k];
        return;
    }
    g -= SZ_XT;
    if (g < SZ_WOT) {
        int o = g & 255, k = g >> 8;
        ws[OFF_WOT + g] = Wout[o * (H_ + C_) + k];
        return;
    }
    g -= SZ_WOT;
    if (g < HB)      { ws[OFF_HA + g] = 0.f;   return; }
    g -= HB;
    if (g < C_*B_)   { ws[OFF_RA + g] = 0.f;   return; }
    g -= C_*B_;
    if (g < SZ_CT)   { ws[OFF_CT + g] = 0.f;   return; }   // hT
    g -= SZ_CT;
    if (g < SZ_M)    { ws[OFF_M  + g] = 0.01f; return; }   // (unused: M in LDS)
    g -= SZ_M;
    if (g < 2*SZ_W)  { ws[OFF_WR + g] = 0.f;   return; }
    g -= 2*SZ_W;
    if (g < SZ_BAR)  { ws[OFF_BAR + g] = 0.f;  return; }
    g -= SZ_BAR;
    if (g < P_ * H_) {
        ((__half*)(ws + OFF_WHH))[g] = __float2half(Whead[g]);
        return;
    }
}

// GEMM inner step: one k-column, 4 gate rows x 8 batches into acc.
#define GEMM_STEP(khat, ap) {                                             \
    const float4 a0 = *(const float4*)(ap);                               \
    const float4 a1 = *(const float4*)((ap) + 4);                         \
    const float2 w01 = *(const float2*)&Wt[(khat) * 18 + (rg << 2)];      \
    const float2 w23 = *(const float2*)&Wt[(khat) * 18 + (rg << 2) + 2];  \
    const float wv[4] = {w01.x, w01.y, w23.x, w23.y};                     \
    const float av[8] = {a0.x, a0.y, a0.z, a0.w, a1.x, a1.y, a1.z, a1.w}; \
    _Pragma("unroll")                                                     \
    for (int j = 0; j < 4; ++j)                                           \
        _Pragma("unroll")                                                 \
        for (int bb = 0; bb < 8; ++bb)                                    \
            acc[j][bb] += wv[j] * av[bb]; }

// ---------------- persistent sequential loop -------------------------------
// 160 blocks x 512 threads, point-to-point flag sync.
// h is published in TWO layouts: hA[t][unit][b] (history: gate GEMM +
// out_kernel) and hT[b][unit] (current step only, coalesced for PB staging:
// 32 lines instead of 512 scattered lines).
__global__ __launch_bounds__(512)
void ntm_loop(const float* __restrict__ Wih, const float* __restrict__ Whh,
              const float* __restrict__ bl,  const float* __restrict__ bhead,
              float* __restrict__ ws)
{
    float* xT  = ws + OFF_XT;
    float* hA  = ws + OFF_HA;
    float* rA  = ws + OFF_RA;
    float* hT  = ws + OFF_CT;
    unsigned* bar = (unsigned*)(ws + OFF_BAR);
    unsigned* flag_h = bar;            // [128] stride 16
    unsigned* flag_r = bar + 4096;     // [32]  stride 16
    const unsigned short* whH = (const unsigned short*)(ws + OFF_WHH);

    __shared__ float Wt[K_ * 18];     // gate blocks: weights; PB: M storage
    __shared__ float p_lds[P_];
    __shared__ float wldsR[128];
    __shared__ float wldsW[128];
    __shared__ float h_lds[H_];       // PB: h staging; gates: h_blk staging
    __shared__ unsigned syncf[4];     // LDS flag mirrors

    const int tid  = threadIdx.x;
    const int bi   = blockIdx.x;
    const bool isPB = (bi < NPB);
    const int gi   = bi - NPB;        // gate block index 0..127

    if (tid < 4) syncf[tid] = 0;

    float* Mlds = Wt;                 // PB alias: M[128][MST] = 34.8 KB

    if (!isPB) {
        for (int idx = tid; idx < K_ * 16; idx += 512) {
            int rl = idx & 15, k = idx >> 4;
            int row = (rl & 3) * H_ + gi * 4 + (rl >> 2);
            float v = (k < I_ + C_) ? Wih[row * (I_ + C_) + k]
                                    : Whh[row * H_ + (k - (I_ + C_))];
            Wt[k * 18 + rl] = v;
        }
    } else {
        if (tid < N_) {
            wldsR[tid] = (tid == 0) ? 1.f : 0.f;
            wldsW[tid] = (tid == 0) ? 1.f : 0.f;
        }
        for (int idx = tid; idx < (N_ * C_) / 4; idx += 512) {
            const int n = idx >> 4;
            const int c = (idx & 15) << 2;
            float4 m4 = {0.01f, 0.01f, 0.01f, 0.01f};
            *(float4*)&Mlds[n * MST + c] = m4;
        }
    }
    __syncthreads();   // staging + syncf visible

    const int pair = tid >> 5;        // 0..15
    const int ks   = tid & 31;        // split-K lane
    const int rg   = pair >> 2;       // unit_local 0..3
    const int bg   = pair & 3;        // batch octet 0..3
    const int b0   = bg * 8;          // 8 batches per pair

    float acc[4][8];
    float cr[8] = {0,0,0,0,0,0,0,0};  // LSTM c (ks==0 lanes)
    float bI = 0, bF = 0, bG = 0, bO = 0;
    if (!isPB && ks == 0) {
        const int unit = gi * 4 + rg;
        bI = bl[unit];        bF = bl[H_ + unit];
        bG = bl[2*H_ + unit]; bO = bl[3*H_ + unit];
    }

    if (!isPB) {
        // pre-loop partial(0): x[0] + h[0](=0)
        #pragma unroll
        for (int j = 0; j < 4; ++j)
            #pragma unroll
            for (int bb = 0; bb < 8; ++bb) acc[j][bb] = 0.f;
        const float* xs = xT;
        const float* hs = hA;
        #pragma unroll
        for (int i = 0; i < 8; ++i) {
            const int k = ks + (i << 5);
            GEMM_STEP(k, xs + k * B_ + b0);
        }
        #pragma unroll
        for (int i = 0; i < 16; ++i) {
            const int k = ks + (i << 5);
            GEMM_STEP(320 + k, hs + k * B_ + b0);
        }

        // ================= gate block main loop =================
        for (int t = 0; t < S_; ++t) {
            // wait r[t] (32 PB flags); t=0 trivially satisfied
            wait_flags(flag_r, NPB, (unsigned)t, &syncf[0], tid);

            const float* rs = rA + (size_t)t * C_ * B_;
            #pragma unroll
            for (int i = 0; i < 2; ++i) {
                const int k = ks + (i << 5);
                GEMM_STEP(256 + k, rs + k * B_ + b0);
            }
            #pragma unroll
            for (int j = 0; j < 4; ++j)
                #pragma unroll
                for (int bb = 0; bb < 8; ++bb) {
                    float v = acc[j][bb];
                    v += __shfl_xor(v, 16, 64);
                    v += __shfl_xor(v, 8, 64);
                    v += __shfl_xor(v, 4, 64);
                    v += __shfl_xor(v, 2, 64);
                    v += __shfl_xor(v, 1, 64);
                    acc[j][bb] = v;
                }
            if (ks == 0) {
                const int unit = gi * 4 + rg;
                float hv[8];
                #pragma unroll
                for (int bb = 0; bb < 8; ++bb) {
                    float gI = acc[0][bb] + bI;
                    float gF = acc[1][bb] + bF;
                    float gG = acc[2][bb] + bG;
                    float gO = acc[3][bb] + bO;
                    float cN = sigm(gF) * cr[bb] + sigm(gI) * tanhf(gG);
                    hv[bb] = sigm(gO) * tanhf(cN);
                    cr[bb] = cN;
                }
                // history publish [unit][batch] (4x 8B agent stores)
                float* dst = &hA[(size_t)(t + 1) * HB + unit * B_ + b0];
                #pragma unroll
                for (int q = 0; q < 4; ++q) {
                    union { float f[2]; unsigned long long u; } pk;
                    pk.f[0] = hv[2 * q]; pk.f[1] = hv[2 * q + 1];
                    __hip_atomic_store((unsigned long long*)(dst + 2 * q), pk.u,
                                       __ATOMIC_RELAXED, __HIP_MEMORY_SCOPE_AGENT);
                }
                // stage for transposed publish: h_blk[batch][unit_local]
                #pragma unroll
                for (int bb = 0; bb < 8; ++bb)
                    h_lds[(b0 + bb) * 4 + rg] = hv[bb];
            }
            __syncthreads();           // drains hA stores + h_blk LDS visible
            // transposed publish hT[b][gi*4..+3]: 32 lanes x 2x 8B stores
            if (tid < 32) {
                const float4 h4 = *(const float4*)&h_lds[tid * 4];
                union { float f[2]; unsigned long long u; } p0, p1;
                p0.f[0] = h4.x; p0.f[1] = h4.y;
                p1.f[0] = h4.z; p1.f[1] = h4.w;
                unsigned long long* d =
                    (unsigned long long*)&hT[tid * H_ + gi * 4];
                __hip_atomic_store(d,     p0.u, __ATOMIC_RELAXED,
                                   __HIP_MEMORY_SCOPE_AGENT);
                __hip_atomic_store(d + 1, p1.u, __ATOMIC_RELAXED,
                                   __HIP_MEMORY_SCOPE_AGENT);
            }
            __syncthreads();           // drains hT stores
            if (tid == 0) {
                asm volatile("s_waitcnt vmcnt(0) lgkmcnt(0)" ::: "memory");
                __hip_atomic_store(&flag_h[gi * 16], (unsigned)(t + 1),
                                   __ATOMIC_RELAXED, __HIP_MEMORY_SCOPE_AGENT);
            }
            // wait full h[t+1] (128 gate flags), then next partial
            wait_flags(flag_h, NGATE, (unsigned)(t + 1), &syncf[2], tid);

            #pragma unroll
            for (int j = 0; j < 4; ++j)
                #pragma unroll
                for (int bb = 0; bb < 8; ++bb) acc[j][bb] = 0.f;
            if (t + 1 < S_) {
                const float* xs2 = xT + (size_t)(t + 1) * I_ * B_;
                const float* hs2 = hA + (size_t)(t + 1) * HB;
                #pragma unroll
                for (int i = 0; i < 8; ++i) {
                    const int k = ks + (i << 5);
                    GEMM_STEP(k, xs2 + k * B_ + b0);
                }
                #pragma unroll
                for (int i = 0; i < 16; ++i) {
                    const int k = ks + (i << 5);
                    GEMM_STEP(320 + k, hs2 + k * B_ + b0);
                }
            }
        }
        return;
    }

    // ================= PB block main loop =================
    const int b = bi;
    for (int t = 0; t < S_; ++t) {
        wait_flags(flag_h, NGATE, (unsigned)(t + 1), &syncf[0], tid);

        // stage h column from transposed buffer: contiguous, 4 lines/wave
        h_lds[tid] = __hip_atomic_load(&hT[b * H_ + tid], __ATOMIC_RELAXED,
                                       __HIP_MEMORY_SCOPE_AGENT);
        __syncthreads();

        // head GEMM (fp16 weights): p = W_head @ h + b_head, 2 thr/row
        {
            const int sub  = tid & 1;
            const int row0 = tid >> 1;
            const float* hb = &h_lds[sub * 256];
            #pragma unroll
            for (int rep = 0; rep < 2; ++rep) {
                const int row = (rep == 0) ? row0
                              : ((row0 < P_ - 256) ? row0 + 256 : -1);
                if (row >= 0) {
                    const unsigned short* wrow = whH + row * H_ + sub * 256;
                    float acch = 0.f;
                    #pragma unroll 4
                    for (int k2 = 0; k2 < 256; k2 += 8) {
                        float4 raw = *(const float4*)&wrow[k2];
                        const __half2* hp = (const __half2*)&raw;
                        float2 f0 = __half22float2(hp[0]);
                        float2 f1 = __half22float2(hp[1]);
                        float2 f2 = __half22float2(hp[2]);
                        float2 f3 = __half22float2(hp[3]);
                        acch += f0.x * hb[k2]     + f0.y * hb[k2 + 1]
                              + f1.x * hb[k2 + 2] + f1.y * hb[k2 + 3]
                              + f2.x * hb[k2 + 4] + f2.y * hb[k2 + 5]
                              + f3.x * hb[k2 + 6] + f3.y * hb[k2 + 7];
                    }
                    acch += __shfl_xor(acch, 1, 64);
                    if (sub == 0) p_lds[row] = acch + bhead[row];
                }
            }
        }
        __syncthreads();

        // dual-pass addressing: grp0=read head, grp1=write head (concurrent)
        {
            float* wtmpA = h_lds;            // alias (h_lds dead)
            float* sbufA = h_lds + 256;
            const int grp = (tid >> 7) & 1;
            const int l   = tid & 127;
            const bool act256 = (tid < 256);
            const int o = grp ? 70 : 0;
            const int widx = (tid >> 6) & 1;

            float z = 0.f, gate = 0.f, s0 = 0.f, s1 = 0.f, s2 = 0.f,
                  gamma = 1.f;
            if (act256) {
                float beta = splus(p_lds[o + 64]);
                gate = sigm(p_lds[o + 65]);
                float sa = p_lds[o + 66], sbv = p_lds[o + 67],
                      sc = p_lds[o + 68];
                float sm3 = fmaxf(sa, fmaxf(sbv, sc));
                float ea = __expf(sa - sm3), eb = __expf(sbv - sm3),
                      ec = __expf(sc - sm3);
                float es3 = ea + eb + ec;
                s0 = ea / es3; s1 = eb / es3; s2 = ec / es3;
                gamma = 1.f + splus(p_lds[o + 69]);
                float kk = 0.f;
                #pragma unroll 8
                for (int c = 0; c < C_; ++c) {
                    float kv = p_lds[o + c]; kk += kv * kv;
                }
                const float knorm = sqrtf(kk) + EPSX;
                float dot = 0.f, mm = 0.f;
                #pragma unroll
                for (int c = 0; c < C_; c += 4) {
                    float4 m4 = *(const float4*)&Mlds[l * MST + c];
                    dot += m4.x * p_lds[o + c]     + m4.y * p_lds[o + c + 1]
                         + m4.z * p_lds[o + c + 2] + m4.w * p_lds[o + c + 3];
                    mm  += m4.x * m4.x + m4.y * m4.y + m4.z * m4.z
                         + m4.w * m4.w;
                }
                z = beta * (dot / ((sqrtf(mm) + EPSX) * knorm));
            }
            float zm = wave_max(z);
            if (act256 && (tid & 63) == 0) sbufA[grp * 8 + widx] = zm;
            __syncthreads();
            const float zmax = fmaxf(sbufA[grp * 8], sbufA[grp * 8 + 1]);
            float ev = act256 ? __expf(z - zmax) : 0.f;
            float es = wave_sum(ev);
            if (act256 && (tid & 63) == 0) sbufA[grp * 8 + 2 + widx] = es;
            __syncthreads();
            const float esum = sbufA[grp * 8 + 2] + sbufA[grp * 8 + 3];
            if (act256) {
                float wc = ev / esum;
                float wprev = grp ? wldsW[l] : wldsR[l];
                wtmpA[grp * 128 + l] = gate * wc + (1.f - gate) * wprev;
            }
            __syncthreads();
            float wp = 0.f;
            if (act256) {
                float wsft = s0 * wtmpA[grp * 128 + ((l + 1) & 127)]
                           + s1 * wtmpA[grp * 128 + l]
                           + s2 * wtmpA[grp * 128 + ((l - 1) & 127)];
                wp = __powf(wsft + EPSX, gamma);
            }
            float ps = wave_sum(wp);
            if (act256 && (tid & 63) == 0) sbufA[grp * 8 + 4 + widx] = ps;
            __syncthreads();
            const float psum = sbufA[grp * 8 + 4] + sbufA[grp * 8 + 5];
            if (act256) {
                float wn = wp / psum;
                if (grp) wldsW[l] = wn; else wldsR[l] = wn;
            }
            __syncthreads();
        }

        // M = M*(1 - w_w e) + w_w a   (in LDS, no atomics)
        for (int idx = tid; idx < (N_ * C_) / 4; idx += 512) {
            const int n = idx >> 4;
            const int c = (idx & 15) << 2;
            const float wwn = wldsW[n];
            float4 m4 = *(float4*)&Mlds[n * MST + c];
            m4.x = m4.x * (1.f - wwn * sigm(p_lds[140 + c]))     + wwn * p_lds[204 + c];
            m4.y = m4.y * (1.f - wwn * sigm(p_lds[140 + c + 1])) + wwn * p_lds[204 + c + 1];
            m4.z = m4.z * (1.f - wwn * sigm(p_lds[140 + c + 2])) + wwn * p_lds[204 + c + 2];
            m4.w = m4.w * (1.f - wwn * sigm(p_lds[140 + c + 3])) + wwn * p_lds[204 + c + 3];
            *(float4*)&Mlds[n * MST + c] = m4;
        }
        __syncthreads();

        // r = w_r @ M_new (LDS reads, shuffle reduce) -> publish
        {
            const int c = tid >> 3, ns = tid & 7;
            float accr = 0.f;
            #pragma unroll
            for (int i = 0; i < 16; ++i) {
                const int n = ns + 8 * i;
                accr += wldsR[n] * Mlds[n * MST + c];
            }
            accr += __shfl_xor(accr, 4, 64);
            accr += __shfl_xor(accr, 2, 64);
            accr += __shfl_xor(accr, 1, 64);
            if (ns == 0)
                __hip_atomic_store(&rA[(size_t)(t + 1) * C_ * B_ + c * B_ + b],
                                   accr, __ATOMIC_RELAXED,
                                   __HIP_MEMORY_SCOPE_AGENT);
        }
        __syncthreads();               // drain r stores
        if (tid == 0) {
            asm volatile("s_waitcnt vmcnt(0) lgkmcnt(0)" ::: "memory");
            __hip_atomic_store(&flag_r[b * 16], (unsigned)(t + 1),
                               __ATOMIC_RELAXED, __HIP_MEMORY_SCOPE_AGENT);
        }
    }
}

// ---------------- final output GEMM ----------------
__global__ __launch_bounds__(256)
void out_kernel(const float* __restrict__ ws, const float* __restrict__ bout,
                float* __restrict__ out)
{
    __shared__ float actL[(H_ + C_) * 16];
    const float* hA  = ws + OFF_HA;
    const float* rA  = ws + OFF_RA;
    const float* WoT = ws + OFF_WOT;
    const int t   = blockIdx.x >> 1;
    const int bh  = blockIdx.x & 1;
    const int tid = threadIdx.x;

    for (int idx = tid; idx < (H_ + C_) * 16; idx += 256) {
        const int k = idx >> 4, bl2 = idx & 15, b = bh * 16 + bl2;
        float v = (k < H_) ? hA[(size_t)(t + 1) * HB + k * B_ + b]
                           : rA[(size_t)(t + 1) * C_ * B_ + (k - H_) * B_ + b];
        actL[k * 16 + bl2] = v;
    }
    __syncthreads();

    const int ot = tid & 63, bt = tid >> 6;
    const int o0 = ot * 4, bl0 = bt * 4;
    float acc[4][4] = {{0,0,0,0},{0,0,0,0},{0,0,0,0},{0,0,0,0}};
    for (int k = 0; k < H_ + C_; ++k) {
        const float4 w4 = *(const float4*)&WoT[k * O_ + o0];
        const float4 a4 = *(const float4*)&actL[k * 16 + bl0];
        const float wv[4] = {w4.x, w4.y, w4.z, w4.w};
        const float av[4] = {a4.x, a4.y, a4.z, a4.w};
        #pragma unroll
        for (int j = 0; j < 4; ++j)
            #pragma unroll
            for (int bb = 0; bb < 4; ++bb)
                acc[j][bb] += wv[j] * av[bb];
    }
    const float4 bo = *(const float4*)&bout[o0];
    #pragma unroll
    for (int bb = 0; bb < 4; ++bb) {
        const int b = bh * 16 + bl0 + bb;
        float4 res;
        res.x = acc[0][bb] + bo.x;
        res.y = acc[1][bb] + bo.y;
        res.z = acc[2][bb] + bo.z;
        res.w = acc[3][bb] + bo.w;
        *(float4*)&out[((size_t)b * S_ + t) * O_ + o0] = res;
    }
}

extern "C" void kernel_launch(void* const* d_in, const int* in_sizes, int n_in,
                              void* d_out, int out_size, void* d_ws, size_t ws_size,
                              hipStream_t stream)
{
    const float* x    = (const float*)d_in[0];
    const float* Wih  = (const float*)d_in[1];
    const float* Whh  = (const float*)d_in[2];
    const float* bl   = (const float*)d_in[3];
    const float* Whd  = (const float*)d_in[4];
    const float* bhd  = (const float*)d_in[5];
    const float* Wout = (const float*)d_in[6];
    const float* bout = (const float*)d_in[7];
    float* ws  = (float*)d_ws;
    float* out = (float*)d_out;

    prep_kernel<<<10529, 256, 0, stream>>>(x, Wout, Whd, ws);

    void* args[] = { (void*)&Wih, (void*)&Whh, (void*)&bl,
                     (void*)&bhd, (void*)&ws };
    (void)hipLaunchCooperativeKernel((void*)ntm_loop, dim3(NBLK), dim3(512), args, 0, stream);

    out_kernel<<<512, 256, 0, stream>>>(ws, bout, out);
}